// Round 8
// baseline (122.348 us; speedup 1.0000x reference)
//
#include <hip/hip_runtime.h>
#include <hip/hip_bf16.h>

typedef __attribute__((ext_vector_type(8))) short bf16x8;
typedef __attribute__((ext_vector_type(4))) float f32x4;

#define L_SEQ 512
#define N_IN 12
#define S_DIM 128
#define M_OUT 12
#define LPAD 40           // shorts per n-row (80B -> uniform quad-bank spread)
#define KT_STRIDE (16*LPAD)

// RNE f32->bf16 (cold paths)
__device__ inline short f2bf(float f) {
    union { float f; unsigned u; } q; q.f = f;
    unsigned r = (q.u + 0x7fffu + ((q.u >> 16) & 1u)) >> 16;
    return (short)r;
}
// packed f32x2 -> 2xbf16 (RNE), one VALU op
__device__ inline unsigned cvtpk(float lo, float hi) {
    unsigned r;
    asm("v_cvt_pk_bf16_f32 %0, %1, %2" : "=v"(r) : "v"(lo), "v"(hi));
    return r;
}
// B-slot (kt,q,j) holds state row s = 32kt + 16(j>>2) + 4q + (j&3).
// Same-lane D->B chaining: E2E-verified R4/R5/R7.
__device__ inline int s_perm(int kt, int q, int j) {
    return 32 * kt + 16 * (j >> 2) + 4 * q + (j & 3);
}
// lgkm-only barrier: does NOT drain vmcnt (helpers' x prefetch stays in flight)
__device__ inline void block_sync() {
    asm volatile("s_waitcnt lgkmcnt(0)" ::: "memory");
    __builtin_amdgcn_s_barrier();
}

__global__ __launch_bounds__(512, 1)
void elman_kernel(const float* __restrict__ x,
                  const float* __restrict__ a0,
                  const float* __restrict__ U_w,
                  const float* __restrict__ U_b,
                  const float* __restrict__ W_w,
                  const float* __restrict__ W_b,
                  const float* __restrict__ V_w,
                  const float* __restrict__ V_b,
                  float* __restrict__ out)
{
    __shared__ __align__(16) short stx[2][4 * KT_STRIDE];  // state exchange (ping-pong)
    __shared__ __align__(16) short xr[4][64 * 8];          // xf fragment ring (4 slots)

    const int tid  = threadIdx.x;
    const int w    = tid >> 6;        // waves 0..3 compute, 4..7 x-stage helpers
    const int l    = tid & 63;
    const int n    = l & 15;
    const int q    = l >> 4;
    const bool qodd = (q & 1);
    const int b0   = blockIdx.x * 16;
    const int row  = b0 + n;
    const int fragoff = n * LPAD + q * 8;

    const float* xpA = x + (size_t)row * L_SEQ * N_IN + (q & 1) * 8;
    const float* xpB = xpA + (qodd ? 0 : 4);

#define MAKE_XF(XF, XA, XB) do {                                                       \
    union { unsigned uu[4]; bf16x8 v; } xu_;                                           \
    xu_.uu[0] = cvtpk(XA.x, XA.y);                                                     \
    xu_.uu[1] = cvtpk(XA.z, XA.w);                                                     \
    xu_.uu[2] = qodd ? 0x00003F80u : cvtpk(XB.x, XB.y);  /* k==12 -> bf16(1.0) */      \
    xu_.uu[3] = qodd ? 0u          : cvtpk(XB.z, XB.w);                                \
    XF = xu_.v;                                                                        \
} while (0)

    // ---- compute waves: step-invariant W/U fragments (wave w owns s-rows [32w,32w+32)) ----
    bf16x8 wf[2][4]; bf16x8 uf[2];
    if (w < 4) {
        #pragma unroll
        for (int h = 0; h < 2; ++h) {
            const int c = (2 * w + h) * 16 + n;
            #pragma unroll
            for (int li = 0; li < 4; ++li) {
                const int kt = (w + li) & 3;
                #pragma unroll
                for (int j = 0; j < 8; ++j)
                    wf[h][li][j] = f2bf(W_w[(size_t)s_perm(kt, q, j) * S_DIM + c]);
            }
            #pragma unroll
            for (int j = 0; j < 8; ++j) {
                const int k = q * 8 + j;
                float v;
                if (k < N_IN)       v = U_w[(size_t)k * S_DIM + c];
                else if (k == N_IN) v = W_b[c] + U_b[c];   // bias via x-slot k=12 == 1.0
                else                v = 0.f;
                uf[h][j] = f2bf(v);
            }
        }
    }

    // ---- stage a0 into buf0 (exchange layout) ----
    for (int idx = tid; idx < 4 * 16 * 32; idx += 512) {
        const int kt = idx >> 9, r = (idx >> 5) & 15, qj = idx & 31;
        const int s = s_perm(kt, qj >> 3, qj & 7);
        stx[0][kt * KT_STRIDE + r * LPAD + qj] = f2bf(a0[(size_t)(b0 + r) * S_DIM + s]);
    }

    // ---- helper prologue: prestage xf(0), xf(1); load first in-flight pair ----
    float4 xa, xb;
    if (w >= 4) {
        const int h = w & 3;
        if (h < 2) {
            float4 pa = *(const float4*)(xpA + (size_t)h * N_IN);
            float4 pb = *(const float4*)(xpB + (size_t)h * N_IN);
            bf16x8 xf; MAKE_XF(xf, pa, pb);
            *(bf16x8*)&xr[h][l * 8] = xf;
        }
        const int sf = ((h + 2) & 3) + 2;   // h: 0->4, 1->5, 2->2, 3->3
        xa = *(const float4*)(xpA + (size_t)sf * N_IN);
        xb = *(const float4*)(xpB + (size_t)sf * N_IN);
    }
    block_sync();

    // ---- compute prologue ----
    bf16x8 stOwn, stf1, stf2, stf3, xfc;
    f32x4 accU0, accU1;
    if (w < 4) {
        const short* rd = &stx[0][0];
        stOwn = *(const bf16x8*)&rd[((w + 0) & 3) * KT_STRIDE + fragoff];
        stf1  = *(const bf16x8*)&rd[((w + 1) & 3) * KT_STRIDE + fragoff];
        stf2  = *(const bf16x8*)&rd[((w + 2) & 3) * KT_STRIDE + fragoff];
        stf3  = *(const bf16x8*)&rd[((w + 3) & 3) * KT_STRIDE + fragoff];
        bf16x8 xf0 = *(const bf16x8*)&xr[0][l * 8];
        xfc        = *(const bf16x8*)&xr[1][l * 8];
        f32x4 z = {0.f, 0.f, 0.f, 0.f};
        accU0 = __builtin_amdgcn_mfma_f32_16x16x32_bf16(uf[0], xf0, z, 0, 0, 0);
        accU1 = __builtin_amdgcn_mfma_f32_16x16x32_bf16(uf[1], xf0, z, 0, 0, 0);
    }

    // ---- main recurrence ----
    for (int t = 0; t < L_SEQ; t += 4) {
        #pragma unroll
        for (int u = 0; u < 4; ++u) {
            const int tt = t + u;
            if (w < 4) {
                __builtin_amdgcn_s_setprio(1);
                f32x4 z = {0.f, 0.f, 0.f, 0.f};
                // W block in operand-arrival order: own (reg) -> stf1 -> stf2 -> stf3
                f32x4 c0a = __builtin_amdgcn_mfma_f32_16x16x32_bf16(wf[0][0], stOwn, accU0, 0, 0, 0);
                f32x4 c1a = __builtin_amdgcn_mfma_f32_16x16x32_bf16(wf[1][0], stOwn, accU1, 0, 0, 0);
                c0a = __builtin_amdgcn_mfma_f32_16x16x32_bf16(wf[0][1], stf1, c0a, 0, 0, 0);
                c1a = __builtin_amdgcn_mfma_f32_16x16x32_bf16(wf[1][1], stf1, c1a, 0, 0, 0);
                f32x4 c0b = __builtin_amdgcn_mfma_f32_16x16x32_bf16(wf[0][2], stf2, z, 0, 0, 0);
                f32x4 c1b = __builtin_amdgcn_mfma_f32_16x16x32_bf16(wf[1][2], stf2, z, 0, 0, 0);
                c0b = __builtin_amdgcn_mfma_f32_16x16x32_bf16(wf[0][3], stf3, c0b, 0, 0, 0);
                c1b = __builtin_amdgcn_mfma_f32_16x16x32_bf16(wf[1][3], stf3, c1b, 0, 0, 0);
                // next-step U.x LAST: xfc read->use window spans the whole W block
                accU0 = __builtin_amdgcn_mfma_f32_16x16x32_bf16(uf[0], xfc, z, 0, 0, 0);
                accU1 = __builtin_amdgcn_mfma_f32_16x16x32_bf16(uf[1], xfc, z, 0, 0, 0);
                // relu + pack own 32-row D tile -> next-step B k-tile (same lane, s_perm)
                union { unsigned uu[4]; bf16x8 v; } su;
                su.uu[0] = cvtpk(fmaxf(c0a[0] + c0b[0], 0.f), fmaxf(c0a[1] + c0b[1], 0.f));
                su.uu[1] = cvtpk(fmaxf(c0a[2] + c0b[2], 0.f), fmaxf(c0a[3] + c0b[3], 0.f));
                su.uu[2] = cvtpk(fmaxf(c1a[0] + c1b[0], 0.f), fmaxf(c1a[1] + c1b[1], 0.f));
                su.uu[3] = cvtpk(fmaxf(c1a[2] + c1b[2], 0.f), fmaxf(c1a[3] + c1b[3], 0.f));
                stOwn = su.v;
                *(bf16x8*)&stx[(tt + 1) & 1][w * KT_STRIDE + fragoff] = stOwn;
                __builtin_amdgcn_s_setprio(0);
            } else {
                // helper h acts when h == (u+2)&3: write xf(tt+2), load x(tt+6)
                if ((w & 3) == ((u + 2) & 3)) {
                    bf16x8 xf; MAKE_XF(xf, xa, xb);
                    *(bf16x8*)&xr[(tt + 2) & 3][l * 8] = xf;
                    const int s2 = (tt + 6 < L_SEQ) ? (tt + 6) : (L_SEQ - 1);
                    xa = *(const float4*)(xpA + (size_t)s2 * N_IN);
                    xb = *(const float4*)(xpB + (size_t)s2 * N_IN);
                }
            }
            block_sync();
            if (w < 4) {
                // read order == consumption order: stf1 (pos 3) ... xfc (pos 9, next body)
                const short* rd = &stx[(tt + 1) & 1][0];
                stf1 = *(const bf16x8*)&rd[((w + 1) & 3) * KT_STRIDE + fragoff];
                stf2 = *(const bf16x8*)&rd[((w + 2) & 3) * KT_STRIDE + fragoff];
                stf3 = *(const bf16x8*)&rd[((w + 3) & 3) * KT_STRIDE + fragoff];
                xfc  = *(const bf16x8*)&xr[(tt + 2) & 3][l * 8];
            }
        }
    }

    // ---- epilogue: yT = V^T @ aT_L + V_b.  Wave 0 (its li order == physical kt). ----
    if (w == 0) {
        f32x4 acc = {0.f, 0.f, 0.f, 0.f};
        #pragma unroll
        for (int li = 0; li < 4; ++li) {
            bf16x8 vf;
            #pragma unroll
            for (int j = 0; j < 8; ++j)
                vf[j] = (n < M_OUT)
                      ? f2bf(V_w[(size_t)s_perm(li, q, j) * M_OUT + n])
                      : (short)0;
            const bf16x8 stt = (li == 0) ? stOwn : (li == 1) ? stf1 : (li == 2) ? stf2 : stf3;
            acc = __builtin_amdgcn_mfma_f32_16x16x32_bf16(vf, stt, acc, 0, 0, 0);
        }
        #pragma unroll
        for (int j = 0; j < 4; ++j) {
            const int m = 4 * q + j;
            if (m < M_OUT)
                out[(size_t)row * M_OUT + m] = acc[j] + V_b[m];
        }
    }
#undef MAKE_XF
}

extern "C" void kernel_launch(void* const* d_in, const int* in_sizes, int n_in,
                              void* d_out, int out_size, void* d_ws, size_t ws_size,
                              hipStream_t stream) {
    const float* x   = (const float*)d_in[0];
    const float* a0  = (const float*)d_in[1];
    const float* U_w = (const float*)d_in[2];
    const float* U_b = (const float*)d_in[3];
    const float* W_w = (const float*)d_in[4];
    const float* W_b = (const float*)d_in[5];
    const float* V_w = (const float*)d_in[6];
    const float* V_b = (const float*)d_in[7];
    float* out = (float*)d_out;

    hipLaunchKernelGGL(elman_kernel, dim3(4096 / 16), dim3(512), 0, stream,
                       x, a0, U_w, U_b, W_w, W_b, V_w, V_b, out);
}